// Round 4
// baseline (693.558 us; speedup 1.0000x reference)
//
#include <hip/hip_runtime.h>
#include <cstdint>
#include <cstddef>

#define S_TOK 8192
#define DIM   2048
#define NE    64
#define CAP   128
#define KSPLIT 2
#define BS    32   // tokens per GEMM block
#define DT    32   // D-tile per GEMM iteration

// ---- workspace layout (float/int32 units) ----
#define OFF_PART   0              // [KSPLIT][S_TOK][NE] = 1,048,576
#define OFF_IDX    1048576        // [S_TOK] int
#define OFF_GATE   1056768        // [S_TOK] float
#define OFF_LOC    1064960        // [S_TOK] int
#define OFF_MEPART 1073152        // [256][NE] float (per-wave partial me sums)
#define OFF_PROD   1089536        // [NE] float

// ---------------- GEMM: logits partial = x @ wg^T (split-K) ----------------
__global__ __launch_bounds__(256) void gemm_logits(
    const float* __restrict__ x, const float* __restrict__ wg,
    float* __restrict__ part)
{
    __shared__ float xs[BS][DT + 1];
    __shared__ float wsh[NE][DT + 1];

    const int sb  = blockIdx.x * BS;
    const int k   = blockIdx.y;
    const int d0  = k * (DIM / KSPLIT);
    const int tid = threadIdx.x;

    const int s_loc = (tid >> 4) * 2;
    const int e_loc = (tid & 15) * 4;

    float acc[2][4] = {{0.f,0.f,0.f,0.f},{0.f,0.f,0.f,0.f}};

    for (int t = 0; t < DIM / KSPLIT; t += DT) {
        {
            const int r = tid >> 3;
            const int c = (tid & 7) * 4;
            const float4 v = *reinterpret_cast<const float4*>(
                &x[(size_t)(sb + r) * DIM + d0 + t + c]);
            xs[r][c]   = v.x; xs[r][c+1] = v.y;
            xs[r][c+2] = v.z; xs[r][c+3] = v.w;
        }
        {
            const int r = tid >> 2;
            const int c = (tid & 3) * 8;
            const float4 v0 = *reinterpret_cast<const float4*>(
                &wg[(size_t)r * DIM + d0 + t + c]);
            const float4 v1 = *reinterpret_cast<const float4*>(
                &wg[(size_t)r * DIM + d0 + t + c + 4]);
            wsh[r][c]   = v0.x; wsh[r][c+1] = v0.y;
            wsh[r][c+2] = v0.z; wsh[r][c+3] = v0.w;
            wsh[r][c+4] = v1.x; wsh[r][c+5] = v1.y;
            wsh[r][c+6] = v1.z; wsh[r][c+7] = v1.w;
        }
        __syncthreads();
        #pragma unroll
        for (int d = 0; d < DT; ++d) {
            const float xv0 = xs[s_loc][d];
            const float xv1 = xs[s_loc + 1][d];
            const float w0 = wsh[e_loc][d];
            const float w1 = wsh[e_loc + 1][d];
            const float w2 = wsh[e_loc + 2][d];
            const float w3 = wsh[e_loc + 3][d];
            acc[0][0] += xv0 * w0; acc[0][1] += xv0 * w1;
            acc[0][2] += xv0 * w2; acc[0][3] += xv0 * w3;
            acc[1][0] += xv1 * w0; acc[1][1] += xv1 * w1;
            acc[1][2] += xv1 * w2; acc[1][3] += xv1 * w3;
        }
        __syncthreads();
    }
    #pragma unroll
    for (int i = 0; i < 2; ++i)
        #pragma unroll
        for (int j = 0; j < 4; ++j)
            part[((size_t)k * S_TOK + sb + s_loc + i) * NE + e_loc + j] = acc[i][j];
}

// ------- softmax + argmax per token (wave = token, lane = expert), no atomics -------
__global__ __launch_bounds__(256) void softmax_top1(
    const float* __restrict__ part, int* __restrict__ idx,
    float* __restrict__ gate, float* __restrict__ me_part)
{
    const int lane = threadIdx.x & 63;
    const int wid  = threadIdx.x >> 6;
    const int gw   = blockIdx.x * 4 + wid;    // global wave id, 0..255

    float me_acc = 0.f;
    for (int s = gw; s < S_TOK; s += 256) {
        const float l = part[(size_t)s * NE + lane]
                      + part[((size_t)S_TOK + s) * NE + lane];
        float m = l;
        #pragma unroll
        for (int o = 32; o; o >>= 1) m = fmaxf(m, __shfl_xor(m, o));
        const float ex = __expf(l - m);
        float sum = ex;
        #pragma unroll
        for (int o = 32; o; o >>= 1) sum += __shfl_xor(sum, o);
        float bv = l; int bi = lane;
        #pragma unroll
        for (int o = 32; o; o >>= 1) {
            const float ov = __shfl_xor(bv, o);
            const int   oi = __shfl_xor(bi, o);
            if (ov > bv || (ov == bv && oi < bi)) { bv = ov; bi = oi; }
        }
        const float g = ex / sum;
        me_acc += g;
        if (lane == bi) {
            idx[s]  = bi;
            gate[s] = g;
        }
    }
    me_part[(size_t)gw * NE + lane] = me_acc;   // non-atomic per-wave partial
}

// ------- per-expert prefix scan over tokens (capacity positions) + me reduce -------
__global__ __launch_bounds__(256) void scan_expert(
    const int* __restrict__ idx, const float* __restrict__ me_part,
    int* __restrict__ loc, float* __restrict__ prod)
{
    const int e    = blockIdx.x;
    const int tid  = threadIdx.x;
    const int lane = tid & 63;
    const int wid  = tid >> 6;
    __shared__ int   wsum[4];
    __shared__ float redf[4];

    // reduce me_part[:, e] over 256 waves
    float mp = me_part[(size_t)tid * NE + e];
    #pragma unroll
    for (int o = 32; o; o >>= 1) mp += __shfl_xor(mp, o);
    if (lane == 0) redf[wid] = mp;

    int running = 0;
    for (int c = 0; c < S_TOK; c += 256) {
        const int s = c + tid;
        const bool match = (idx[s] == e);
        const unsigned long long b = __ballot(match);
        const int before = __popcll(b & ((1ULL << lane) - 1ULL));
        if (lane == 0) wsum[wid] = __popcll(b);
        __syncthreads();
        int woff = 0;
        #pragma unroll
        for (int w = 0; w < 4; ++w) if (w < wid) woff += wsum[w];
        const int tot = wsum[0] + wsum[1] + wsum[2] + wsum[3];
        if (match) {
            const int pos = running + woff + before;
            loc[s] = (pos < CAP) ? pos : -1;
        }
        running += tot;
        __syncthreads();
    }
    if (tid == 0) {
        const float me = (redf[0] + redf[1] + redf[2] + redf[3]) / (float)S_TOK;
        const float ce = (float)running / (float)S_TOK;
        prod[e] = me * ce;
    }
}

// ------- fused zero + sparse scatter + l_aux: one block per token -------
__global__ __launch_bounds__(256) void zero_scatter(
    const int* __restrict__ idx, const int* __restrict__ loc,
    const float* __restrict__ gate, const float* __restrict__ prod,
    float* __restrict__ out)
{
    const int s   = blockIdx.x;
    const int tid = threadIdx.x;
    float* cslab = out + 1 + (size_t)s * (NE * CAP);
    float* dslab = cslab + (size_t)S_TOK * NE * CAP;

    // slab base is (4 mod 16)-aligned: 3-elem head, 2047 float4 body, 1-elem tail
    const float4 z = {0.f, 0.f, 0.f, 0.f};
    if (tid < 3)        { cslab[tid]  = 0.f; dslab[tid]  = 0.f; }
    else if (tid == 3)  { cslab[8191] = 0.f; dslab[8191] = 0.f; }
    float4* cb = reinterpret_cast<float4*>(cslab + 3);
    float4* db = reinterpret_cast<float4*>(dslab + 3);
    #pragma unroll
    for (int j = tid; j < 2047; j += 256) { cb[j] = z; db[j] = z; }

    __syncthreads();   // order value-store after all zero-stores

    if (tid == 0) {
        const int l = loc[s];
        if (l >= 0) {
            const int t = idx[s] * CAP + l;
            cslab[t] = gate[s];
            dslab[t] = 1.0f;
        }
    }
    if (s == 0 && tid >= 64 && tid < 128) {       // separate wave computes l_aux
        const int ln = tid - 64;
        float p = prod[ln];
        #pragma unroll
        for (int o = 32; o; o >>= 1) p += __shfl_xor(p, o);
        if (ln == 0) out[0] = p * (float)NE;      // mean_e(me*ce) * E*E
    }
}

extern "C" void kernel_launch(void* const* d_in, const int* in_sizes, int n_in,
                              void* d_out, int out_size, void* d_ws, size_t ws_size,
                              hipStream_t stream)
{
    const float* x  = (const float*)d_in[0];
    const float* wg = (const float*)d_in[1];
    float* out = (float*)d_out;
    float* ws  = (float*)d_ws;

    float* part    = ws + OFF_PART;
    int*   idx     = (int*)(ws + OFF_IDX);
    float* gate    = ws + OFF_GATE;
    int*   loc     = (int*)(ws + OFF_LOC);
    float* me_part = ws + OFF_MEPART;
    float* prod    = ws + OFF_PROD;

    dim3 ggrid(S_TOK / BS, KSPLIT);
    gemm_logits<<<ggrid, 256, 0, stream>>>(x, wg, part);
    softmax_top1<<<64, 256, 0, stream>>>(part, idx, gate, me_part);
    scan_expert<<<NE, 256, 0, stream>>>(idx, me_part, loc, prod);
    zero_scatter<<<S_TOK, 256, 0, stream>>>(idx, loc, gate, prod, out);
}

// Round 5
// 635.745 us; speedup vs baseline: 1.0909x; 1.0909x over previous
//
#include <hip/hip_runtime.h>
#include <cstdint>
#include <cstddef>

#define S_TOK 8192
#define DIM   2048
#define NE    64
#define CAP   128
#define KSPLIT 4
#define BS    64   // tokens per GEMM block
#define DT    32   // D-tile per GEMM iteration
#define XW    36   // xs row stride (floats): 144B, 16B-aligned, 2-way banks max
#define WW    68   // wshT row stride (floats): 272B, 16B-aligned, 2-way banks max

// ---- workspace layout (float/int32 units) ----
#define OFF_PART   0              // [KSPLIT][S_TOK][NE] = 2,097,152
#define OFF_IDX    2097152        // [S_TOK] int
#define OFF_GATE   2105344        // [S_TOK] float
#define OFF_LOC    2113536        // [S_TOK] int
#define OFF_MEPART 2121728        // [512][NE] float (per-wave partial me sums)
#define OFF_PROD   2154496        // [NE] float

// ------------- GEMM: logits partial = x @ wg^T (split-K, reg-tiled 4x4) -------------
__global__ __launch_bounds__(256) void gemm_logits(
    const float* __restrict__ x, const float* __restrict__ wg,
    float* __restrict__ part)
{
    __shared__ float xs[BS][XW];     // x tile, row-major [token][d]
    __shared__ float wshT[DT][WW];   // w tile, TRANSPOSED [d][expert]

    const int sb  = blockIdx.x * BS;
    const int k   = blockIdx.y;
    const int d0  = k * (DIM / KSPLIT);
    const int tid = threadIdx.x;

    const int r = tid >> 3;          // 0..31 (staging row)
    const int c = (tid & 7) * 4;     // 0..28 (staging d-chunk)
    const int ti = tid >> 4;         // 0..15 token tile -> tokens ti*4..+3
    const int ei = tid & 15;         // 0..15 expert tile -> experts ei*4..+3

    float4 acc4[4];
    #pragma unroll
    for (int i = 0; i < 4; ++i) acc4[i] = make_float4(0.f, 0.f, 0.f, 0.f);

    for (int t = 0; t < DIM / KSPLIT; t += DT) {
        // stage x: 64x32 floats, 2 float4/thread, row-major
        {
            const float4 xa = *reinterpret_cast<const float4*>(
                &x[(size_t)(sb + r) * DIM + d0 + t + c]);
            const float4 xb = *reinterpret_cast<const float4*>(
                &x[(size_t)(sb + r + 32) * DIM + d0 + t + c]);
            *reinterpret_cast<float4*>(&xs[r][c])      = xa;
            *reinterpret_cast<float4*>(&xs[r + 32][c]) = xb;
        }
        // stage w: 64x32 floats, transposed into wshT[d][e]
        {
            const float4 w0 = *reinterpret_cast<const float4*>(
                &wg[(size_t)r * DIM + d0 + t + c]);
            const float4 w1 = *reinterpret_cast<const float4*>(
                &wg[(size_t)(r + 32) * DIM + d0 + t + c]);
            wshT[c + 0][r] = w0.x; wshT[c + 1][r] = w0.y;
            wshT[c + 2][r] = w0.z; wshT[c + 3][r] = w0.w;
            wshT[c + 0][r + 32] = w1.x; wshT[c + 1][r + 32] = w1.y;
            wshT[c + 2][r + 32] = w1.z; wshT[c + 3][r + 32] = w1.w;
        }
        __syncthreads();
        #pragma unroll
        for (int dq = 0; dq < DT / 4; ++dq) {
            float4 xv[4], wv[4];
            #pragma unroll
            for (int i = 0; i < 4; ++i)
                xv[i] = *reinterpret_cast<const float4*>(&xs[ti * 4 + i][dq * 4]);
            #pragma unroll
            for (int q = 0; q < 4; ++q)
                wv[q] = *reinterpret_cast<const float4*>(&wshT[dq * 4 + q][ei * 4]);
            #pragma unroll
            for (int i = 0; i < 4; ++i) {
                acc4[i].x += xv[i].x*wv[0].x + xv[i].y*wv[1].x + xv[i].z*wv[2].x + xv[i].w*wv[3].x;
                acc4[i].y += xv[i].x*wv[0].y + xv[i].y*wv[1].y + xv[i].z*wv[2].y + xv[i].w*wv[3].y;
                acc4[i].z += xv[i].x*wv[0].z + xv[i].y*wv[1].z + xv[i].z*wv[2].z + xv[i].w*wv[3].z;
                acc4[i].w += xv[i].x*wv[0].w + xv[i].y*wv[1].w + xv[i].z*wv[2].w + xv[i].w*wv[3].w;
            }
        }
        __syncthreads();
    }
    #pragma unroll
    for (int i = 0; i < 4; ++i)
        *reinterpret_cast<float4*>(
            &part[((size_t)k * S_TOK + sb + ti * 4 + i) * NE + ei * 4]) = acc4[i];
}

// ------- softmax + argmax per token (wave = token, lane = expert), no atomics -------
__global__ __launch_bounds__(256) void softmax_top1(
    const float* __restrict__ part, int* __restrict__ idx,
    float* __restrict__ gate, float* __restrict__ me_part)
{
    const int lane = threadIdx.x & 63;
    const int wid  = threadIdx.x >> 6;
    const int gw   = blockIdx.x * 4 + wid;    // global wave id, 0..511

    float me_acc = 0.f;
    for (int s = gw; s < S_TOK; s += 512) {
        float l = 0.f;
        #pragma unroll
        for (int k = 0; k < KSPLIT; ++k)
            l += part[((size_t)k * S_TOK + s) * NE + lane];
        float m = l;
        #pragma unroll
        for (int o = 32; o; o >>= 1) m = fmaxf(m, __shfl_xor(m, o));
        const float ex = __expf(l - m);
        float sum = ex;
        #pragma unroll
        for (int o = 32; o; o >>= 1) sum += __shfl_xor(sum, o);
        float bv = l; int bi = lane;
        #pragma unroll
        for (int o = 32; o; o >>= 1) {
            const float ov = __shfl_xor(bv, o);
            const int   oi = __shfl_xor(bi, o);
            if (ov > bv || (ov == bv && oi < bi)) { bv = ov; bi = oi; }
        }
        const float g = ex / sum;
        me_acc += g;
        if (lane == bi) {
            idx[s]  = bi;
            gate[s] = g;
        }
    }
    me_part[(size_t)gw * NE + lane] = me_acc;   // non-atomic per-wave partial
}

// ------- per-expert prefix scan over tokens (capacity positions) + me reduce -------
__global__ __launch_bounds__(256) void scan_expert(
    const int* __restrict__ idx, const float* __restrict__ me_part,
    int* __restrict__ loc, float* __restrict__ prod)
{
    const int e    = blockIdx.x;
    const int tid  = threadIdx.x;
    const int lane = tid & 63;
    const int wid  = tid >> 6;
    __shared__ int   wsum[4];
    __shared__ float redf[4];

    // reduce me_part[:, e] over 512 waves
    float mp = me_part[(size_t)tid * NE + e] + me_part[(size_t)(tid + 256) * NE + e];
    #pragma unroll
    for (int o = 32; o; o >>= 1) mp += __shfl_xor(mp, o);
    if (lane == 0) redf[wid] = mp;

    int running = 0;
    for (int c = 0; c < S_TOK; c += 256) {
        const int s = c + tid;
        const bool match = (idx[s] == e);
        const unsigned long long b = __ballot(match);
        const int before = __popcll(b & ((1ULL << lane) - 1ULL));
        if (lane == 0) wsum[wid] = __popcll(b);
        __syncthreads();
        int woff = 0;
        #pragma unroll
        for (int w = 0; w < 4; ++w) if (w < wid) woff += wsum[w];
        const int tot = wsum[0] + wsum[1] + wsum[2] + wsum[3];
        if (match) {
            const int pos = running + woff + before;
            loc[s] = (pos < CAP) ? pos : -1;
        }
        running += tot;
        __syncthreads();
    }
    if (tid == 0) {
        const float me = (redf[0] + redf[1] + redf[2] + redf[3]) / (float)S_TOK;
        const float ce = (float)running / (float)S_TOK;
        prod[e] = me * ce;
    }
}

// ------- fused zero + sparse scatter + l_aux: one block per token -------
__global__ __launch_bounds__(256) void zero_scatter(
    const int* __restrict__ idx, const int* __restrict__ loc,
    const float* __restrict__ gate, const float* __restrict__ prod,
    float* __restrict__ out)
{
    const int s   = blockIdx.x;
    const int tid = threadIdx.x;
    float* cslab = out + 1 + (size_t)s * (NE * CAP);
    float* dslab = cslab + (size_t)S_TOK * NE * CAP;

    // slab base is (4 mod 16)-aligned: 3-elem head, 2047 float4 body, 1-elem tail
    const float4 z = {0.f, 0.f, 0.f, 0.f};
    if (tid < 3)        { cslab[tid]  = 0.f; dslab[tid]  = 0.f; }
    else if (tid == 3)  { cslab[8191] = 0.f; dslab[8191] = 0.f; }
    float4* cb = reinterpret_cast<float4*>(cslab + 3);
    float4* db = reinterpret_cast<float4*>(dslab + 3);
    #pragma unroll
    for (int j = tid; j < 2047; j += 256) { cb[j] = z; db[j] = z; }

    __syncthreads();   // order value-store after all zero-stores

    if (tid == 0) {
        const int l = loc[s];
        if (l >= 0) {
            const int t = idx[s] * CAP + l;
            cslab[t] = gate[s];
            dslab[t] = 1.0f;
        }
    }
    if (s == 0 && tid >= 64 && tid < 128) {       // separate wave computes l_aux
        const int ln = tid - 64;
        float p = prod[ln];
        #pragma unroll
        for (int o = 32; o; o >>= 1) p += __shfl_xor(p, o);
        if (ln == 0) out[0] = p * (float)NE;      // mean_e(me*ce) * E*E
    }
}

extern "C" void kernel_launch(void* const* d_in, const int* in_sizes, int n_in,
                              void* d_out, int out_size, void* d_ws, size_t ws_size,
                              hipStream_t stream)
{
    const float* x  = (const float*)d_in[0];
    const float* wg = (const float*)d_in[1];
    float* out = (float*)d_out;
    float* ws  = (float*)d_ws;

    float* part    = ws + OFF_PART;
    int*   idx     = (int*)(ws + OFF_IDX);
    float* gate    = ws + OFF_GATE;
    int*   loc     = (int*)(ws + OFF_LOC);
    float* me_part = ws + OFF_MEPART;
    float* prod    = ws + OFF_PROD;

    dim3 ggrid(S_TOK / BS, KSPLIT);
    gemm_logits<<<ggrid, 256, 0, stream>>>(x, wg, part);
    softmax_top1<<<128, 256, 0, stream>>>(part, idx, gate, me_part);
    scan_expert<<<NE, 256, 0, stream>>>(idx, me_part, loc, prod);
    zero_scatter<<<S_TOK, 256, 0, stream>>>(idx, loc, gate, prod, out);
}

// Round 7
// 626.914 us; speedup vs baseline: 1.1063x; 1.0141x over previous
//
#include <hip/hip_runtime.h>
#include <cstdint>
#include <cstddef>

#define S_TOK 8192
#define DIM   2048
#define NE    64
#define CAP   128
#define KSPLIT 4
#define BS    64   // tokens per GEMM block
#define DT    32   // D-tile per GEMM iteration
#define XW    36   // xs row stride (floats): 144B, 16B-aligned
#define WW    68   // wshT row stride (floats): 272B, 16B-aligned

// output: [0]=l_aux, [1 .. 1+S*NE*CAP)=combine, then dispatch. 134,217,729 floats.
#define NOUT4 33554432ULL   // float4 count covering floats [0, 134217728)

// ---- workspace layout (float/int32 units) ----
#define OFF_PART   0              // [KSPLIT][S_TOK][NE] = 2,097,152
#define OFF_IDX    2097152        // [S_TOK] int
#define OFF_GATE   2105344        // [S_TOK] float
#define OFF_LOC    2113536        // [S_TOK] int
#define OFF_MEPART 2121728        // [512][NE] float
#define OFF_PROD   2154496        // [NE] float

// ---- GEMM (split-K, 4x4 reg tile) + interleaved zeroing of the 537MB output ----
__global__ __launch_bounds__(256) void gemm_zero(
    const float* __restrict__ x, const float* __restrict__ wg,
    float* __restrict__ part, float* __restrict__ out)
{
    __shared__ float xs[BS][XW];     // x tile [token][d]
    __shared__ float wshT[DT][WW];   // w tile transposed [d][expert]

    const int sb  = blockIdx.x * BS;
    const int k   = blockIdx.y;
    const int d0  = k * (DIM / KSPLIT);
    const int tid = threadIdx.x;
    const int bid = blockIdx.y * (S_TOK / BS) + blockIdx.x;   // 0..511

    const int r = tid >> 3;          // 0..31
    const int c = (tid & 7) * 4;     // 0..28
    const int ti = tid >> 4;         // 0..15
    const int ei = tid & 15;         // 0..15

    // zero-store stream: 256 float4/thread, block chunk = 65536 float4 (1 MB)
    float4* outv = reinterpret_cast<float4*>(out);
    const size_t zbase = (size_t)bid * 65536 + tid;
    const float4 z4 = make_float4(0.f, 0.f, 0.f, 0.f);

    float4 acc4[4];
    #pragma unroll
    for (int i = 0; i < 4; ++i) acc4[i] = z4;

    int it = 0;
    for (int t = 0; t < DIM / KSPLIT; t += DT, ++it) {
        // stage x: 64x32, 2 float4/thread
        {
            const float4 xa = *reinterpret_cast<const float4*>(
                &x[(size_t)(sb + r) * DIM + d0 + t + c]);
            const float4 xb = *reinterpret_cast<const float4*>(
                &x[(size_t)(sb + r + 32) * DIM + d0 + t + c]);
            *reinterpret_cast<float4*>(&xs[r][c])      = xa;
            *reinterpret_cast<float4*>(&xs[r + 32][c]) = xb;
        }
        // stage w transposed
        {
            const float4 w0 = *reinterpret_cast<const float4*>(
                &wg[(size_t)r * DIM + d0 + t + c]);
            const float4 w1 = *reinterpret_cast<const float4*>(
                &wg[(size_t)(r + 32) * DIM + d0 + t + c]);
            wshT[c + 0][r] = w0.x; wshT[c + 1][r] = w0.y;
            wshT[c + 2][r] = w0.z; wshT[c + 3][r] = w0.w;
            wshT[c + 0][r + 32] = w1.x; wshT[c + 1][r + 32] = w1.y;
            wshT[c + 2][r + 32] = w1.z; wshT[c + 3][r + 32] = w1.w;
        }
        __syncthreads();

        // fire-and-forget zero stores: 16 float4 per thread per iteration,
        // coalesced (64 lanes x 16B = 1KB per instr); drain hides under FMA.
        #pragma unroll
        for (int j = 0; j < 16; ++j)
            outv[zbase + (size_t)(it * 16 + j) * 256] = z4;

        #pragma unroll
        for (int dq = 0; dq < DT / 4; ++dq) {
            float4 xv[4], wv[4];
            #pragma unroll
            for (int i = 0; i < 4; ++i)
                xv[i] = *reinterpret_cast<const float4*>(&xs[ti * 4 + i][dq * 4]);
            #pragma unroll
            for (int q = 0; q < 4; ++q)
                wv[q] = *reinterpret_cast<const float4*>(&wshT[dq * 4 + q][ei * 4]);
            #pragma unroll
            for (int i = 0; i < 4; ++i) {
                acc4[i].x += xv[i].x*wv[0].x + xv[i].y*wv[1].x + xv[i].z*wv[2].x + xv[i].w*wv[3].x;
                acc4[i].y += xv[i].x*wv[0].y + xv[i].y*wv[1].y + xv[i].z*wv[2].y + xv[i].w*wv[3].y;
                acc4[i].z += xv[i].x*wv[0].z + xv[i].y*wv[1].z + xv[i].z*wv[2].z + xv[i].w*wv[3].z;
                acc4[i].w += xv[i].x*wv[0].w + xv[i].y*wv[1].w + xv[i].z*wv[2].w + xv[i].w*wv[3].w;
            }
        }
        __syncthreads();
    }
    // last odd float of the output (float index 134,217,728)
    if (bid == 511 && tid == 255) out[4ULL * NOUT4] = 0.f;

    #pragma unroll
    for (int i = 0; i < 4; ++i)
        *reinterpret_cast<float4*>(
            &part[((size_t)k * S_TOK + sb + ti * 4 + i) * NE + ei * 4]) = acc4[i];
}

// ------- softmax + argmax per token (wave = token, lane = expert), no atomics -------
__global__ __launch_bounds__(256) void softmax_top1(
    const float* __restrict__ part, int* __restrict__ idx,
    float* __restrict__ gate, float* __restrict__ me_part)
{
    const int lane = threadIdx.x & 63;
    const int wid  = threadIdx.x >> 6;
    const int gw   = blockIdx.x * 4 + wid;    // 0..511

    float me_acc = 0.f;
    for (int s = gw; s < S_TOK; s += 512) {
        float l = 0.f;
        #pragma unroll
        for (int k = 0; k < KSPLIT; ++k)
            l += part[((size_t)k * S_TOK + s) * NE + lane];
        float m = l;
        #pragma unroll
        for (int o = 32; o; o >>= 1) m = fmaxf(m, __shfl_xor(m, o));
        const float ex = __expf(l - m);
        float sum = ex;
        #pragma unroll
        for (int o = 32; o; o >>= 1) sum += __shfl_xor(sum, o);
        float bv = l; int bi = lane;
        #pragma unroll
        for (int o = 32; o; o >>= 1) {
            const float ov = __shfl_xor(bv, o);
            const int   oi = __shfl_xor(bi, o);
            if (ov > bv || (ov == bv && oi < bi)) { bv = ov; bi = oi; }
        }
        const float g = ex / sum;
        me_acc += g;
        if (lane == bi) {
            idx[s]  = bi;
            gate[s] = g;
        }
    }
    me_part[(size_t)gw * NE + lane] = me_acc;
}

// ------- per-expert prefix scan over tokens (capacity positions) + me reduce -------
__global__ __launch_bounds__(256) void scan_expert(
    const int* __restrict__ idx, const float* __restrict__ me_part,
    int* __restrict__ loc, float* __restrict__ prod)
{
    const int e    = blockIdx.x;
    const int tid  = threadIdx.x;
    const int lane = tid & 63;
    const int wid  = tid >> 6;
    __shared__ int   wsum[4];
    __shared__ float redf[4];

    float mp = me_part[(size_t)tid * NE + e] + me_part[(size_t)(tid + 256) * NE + e];
    #pragma unroll
    for (int o = 32; o; o >>= 1) mp += __shfl_xor(mp, o);
    if (lane == 0) redf[wid] = mp;

    int running = 0;
    for (int c = 0; c < S_TOK; c += 256) {
        const int s = c + tid;
        const bool match = (idx[s] == e);
        const unsigned long long b = __ballot(match);
        const int before = __popcll(b & ((1ULL << lane) - 1ULL));
        if (lane == 0) wsum[wid] = __popcll(b);
        __syncthreads();
        int woff = 0;
        #pragma unroll
        for (int w = 0; w < 4; ++w) if (w < wid) woff += wsum[w];
        const int tot = wsum[0] + wsum[1] + wsum[2] + wsum[3];
        if (match) {
            const int pos = running + woff + before;
            loc[s] = (pos < CAP) ? pos : -1;
        }
        running += tot;
        __syncthreads();
    }
    if (tid == 0) {
        const float me = (redf[0] + redf[1] + redf[2] + redf[3]) / (float)S_TOK;
        const float ce = (float)running / (float)S_TOK;
        prod[e] = me * ce;
    }
}

// ------- sparse scatter (output already zeroed by gemm_zero) + l_aux -------
__global__ __launch_bounds__(256) void scatter_final(
    const int* __restrict__ idx, const int* __restrict__ loc,
    const float* __restrict__ gate, const float* __restrict__ prod,
    float* __restrict__ out)
{
    const int s = blockIdx.x * 256 + threadIdx.x;
    const int l = loc[s];
    if (l >= 0) {
        const size_t off = ((size_t)s * NE + idx[s]) * CAP + l;
        out[1 + off] = gate[s];
        out[1 + (size_t)S_TOK * NE * CAP + off] = 1.0f;
    }
    if (blockIdx.x == 0 && threadIdx.x < 64) {
        float p = prod[threadIdx.x];
        #pragma unroll
        for (int o = 32; o; o >>= 1) p += __shfl_xor(p, o);
        if (threadIdx.x == 0) out[0] = p * (float)NE;   // mean_e(me*ce) * E*E
    }
}

extern "C" void kernel_launch(void* const* d_in, const int* in_sizes, int n_in,
                              void* d_out, int out_size, void* d_ws, size_t ws_size,
                              hipStream_t stream)
{
    const float* x  = (const float*)d_in[0];
    const float* wg = (const float*)d_in[1];
    float* out = (float*)d_out;
    float* ws  = (float*)d_ws;

    float* part    = ws + OFF_PART;
    int*   idx     = (int*)(ws + OFF_IDX);
    float* gate    = ws + OFF_GATE;
    int*   loc     = (int*)(ws + OFF_LOC);
    float* me_part = ws + OFF_MEPART;
    float* prod    = ws + OFF_PROD;

    dim3 ggrid(S_TOK / BS, KSPLIT);
    gemm_zero<<<ggrid, 256, 0, stream>>>(x, wg, part, out);
    softmax_top1<<<128, 256, 0, stream>>>(part, idx, gate, me_part);
    scan_expert<<<NE, 256, 0, stream>>>(idx, me_part, loc, prod);
    scatter_final<<<S_TOK / 256, 256, 0, stream>>>(idx, loc, gate, prod, out);
}